// Round 3
// baseline (1175.878 us; speedup 1.0000x reference)
//
#include <hip/hip_runtime.h>
#include <hip/hip_bf16.h>

typedef __hip_bfloat16 bf16;

#define N_PTS 50000
#define N_ROWS (N_PTS * 16)
#define EPS 1e-5f

__device__ __forceinline__ float bf2f(bf16 x) { return __bfloat162float(x); }
__device__ __forceinline__ bf16 f2bf(float x) { return __float2bfloat16(x); }

struct PtrTable { const void* p[32]; };
struct IntTable { int v[32]; };

// ---- sniff: detect whether float inputs are f32 (flag=1) or bf16 (flag=0) ----
__global__ __launch_bounds__(256) void sniff_kernel(const void* feat, int* flag)
{
    __shared__ int cnt;
    if (threadIdx.x == 0) cnt = 0;
    __syncthreads();
    const unsigned short* u = (const unsigned short*)feat;
    int local = 0;
    #pragma unroll
    for (int j = 0; j < 8; ++j) {
        unsigned short bits = u[2 * (threadIdx.x * 8 + j)];   // even index = low half if f32
        int e = (bits >> 7) & 0xFF;
        if (e >= 140) local++;   // |x| >= 2^13: impossible for sane bf16 data
    }
    atomicAdd(&cnt, local);
    __syncthreads();
    if (threadIdx.x == 0) *flag = (cnt > 16) ? 1 : 0;
}

// ---- canon: copy all float inputs into one canonical bf16 region per flag ----
__global__ __launch_bounds__(256) void canon_kernel(
    const int* __restrict__ flag, PtrTable pt, IntTable sz, IntTable off, bf16* __restrict__ dst)
{
    const bool isf32 = (*flag != 0);
    const int stride = gridDim.x * blockDim.x;
    const int tid0 = blockIdx.x * blockDim.x + threadIdx.x;
    for (int s = 0; s < 32; ++s) {
        const int n = sz.v[s];
        bf16* d = dst + off.v[s];
        if (isf32) {
            const float* src = (const float*)pt.p[s];
            for (int i = tid0; i < n; i += stride) d[i] = f2bf(src[i]);
        } else {
            const bf16* src = (const bf16*)pt.p[s];
            for (int i = tid0; i < n; i += stride) d[i] = src[i];
        }
    }
}

// ---- prep: W_pe[64][4] = pb2_w @ we1_w ; b_pe[4] = pb2_b @ we1_w + we1_b ----
__global__ __launch_bounds__(256) void prep_kernel(
    const bf16* __restrict__ pb2w, const bf16* __restrict__ pb2b,
    const bf16* __restrict__ we1w, const bf16* __restrict__ we1b,
    float* __restrict__ W_pe, float* __restrict__ b_pe)
{
    const int t = threadIdx.x;
    const int k = t >> 2, g = t & 3;
    float s = 0.f;
    for (int j = 0; j < 64; ++j) s += bf2f(pb2w[k * 64 + j]) * bf2f(we1w[j * 4 + g]);
    W_pe[k * 4 + g] = s;
    if (t < 4) {
        float sb = 0.f;
        for (int j = 0; j < 64; ++j) sb += bf2f(pb2b[j]) * bf2f(we1w[j * 4 + t]);
        b_pe[t] = sb + bf2f(we1b[t]);
    }
}

// ---- gemm64: out = f(in) @ W + bias ; f = optional bn(from stats)+relu; out f32 or bf16 ----
__global__ __launch_bounds__(256) void gemm64_kernel(
    const float* __restrict__ inF, const bf16* __restrict__ inB,
    const double* __restrict__ in_stats, const bf16* __restrict__ in_g, const bf16* __restrict__ in_b,
    float in_inv_cnt,
    const bf16* __restrict__ W, const bf16* __restrict__ bias,
    float* __restrict__ outF, bf16* __restrict__ outB,
    double* __restrict__ out_stats, int n)
{
    __shared__ float w_l[64][64];
    __shared__ float in_l[64][64];
    __shared__ float sc_l[64], sh_l[64];
    __shared__ float redS[4][64], redS2[4][64];
    const int t = threadIdx.x;
    const int c = t & 63, rg = t >> 6;

    #pragma unroll
    for (int i = 0; i < 16; ++i) {
        int e = i * 256 + t;
        w_l[e >> 6][e & 63] = bf2f(W[e]);
    }
    if (in_stats && t < 64) {
        float m  = (float)(in_stats[t] * (double)in_inv_cnt);
        float va = (float)(in_stats[64 + t] * (double)in_inv_cnt) - m * m;
        float sc = bf2f(in_g[t]) * rsqrtf(va + EPS);
        sc_l[t] = sc;
        sh_l[t] = bf2f(in_b[t]) - m * sc;
    }
    const int base = blockIdx.x * 64;
    #pragma unroll
    for (int i = 0; i < 16; ++i) {
        int e = i * 256 + t;
        int p = base + (e >> 6);
        float v = 0.f;
        if (p < n) v = inB ? bf2f(inB[p * 64 + (e & 63)]) : inF[p * 64 + (e & 63)];
        in_l[e >> 6][e & 63] = v;
    }
    __syncthreads();
    if (in_stats) {
        #pragma unroll
        for (int i = 0; i < 16; ++i) {
            int e = i * 256 + t;
            float v = in_l[e >> 6][e & 63] * sc_l[e & 63] + sh_l[e & 63];
            in_l[e >> 6][e & 63] = fmaxf(v, 0.f);
        }
        __syncthreads();
    }
    const float bv = bias ? bf2f(bias[c]) : 0.f;
    float ls = 0.f, ls2 = 0.f;
    for (int i = 0; i < 16; ++i) {
        const int pl = rg * 16 + i;
        float acc = bv;
        #pragma unroll
        for (int k = 0; k < 64; ++k) acc += in_l[pl][k] * w_l[k][c];
        const int p = base + pl;
        if (p < n) {
            if (outF) outF[p * 64 + c] = acc;
            else      outB[p * 64 + c] = f2bf(acc);
            ls += acc; ls2 += acc * acc;
        }
    }
    if (out_stats) {
        redS[rg][c] = ls; redS2[rg][c] = ls2;
        __syncthreads();
        if (t < 64) {
            atomicAdd(&out_stats[t], (double)(redS[0][t] + redS[1][t] + redS[2][t] + redS[3][t]));
        } else if (t < 128) {
            int cc = t - 64;
            atomicAdd(&out_stats[64 + cc], (double)(redS2[0][cc] + redS2[1][cc] + redS2[2][cc] + redS2[3][cc]));
        }
    }
}

// ---- qkw1: q = relu(bn(qp)), k = relu(bn(kp)); qw1 = q@we1_w, kw1 = k@we1_w (N,4 each) ----
__global__ __launch_bounds__(256) void qkw1_kernel(
    const bf16* __restrict__ qp, const bf16* __restrict__ kp,
    const double* __restrict__ stQ, const double* __restrict__ stK,
    const bf16* __restrict__ q_g, const bf16* __restrict__ q_be,
    const bf16* __restrict__ k_g, const bf16* __restrict__ k_be,
    const bf16* __restrict__ we1w,
    float* __restrict__ qw1, float* __restrict__ kw1, int n, float inv_cnt)
{
    __shared__ float q_l[64][65];
    __shared__ float k_l[64][65];
    __shared__ float scq[64], shq[64], sck[64], shk[64];
    __shared__ float w1[64][4];
    const int t = threadIdx.x;
    if (t < 64) {
        float m  = (float)(stQ[t] * (double)inv_cnt);
        float va = (float)(stQ[64 + t] * (double)inv_cnt) - m * m;
        float sc = bf2f(q_g[t]) * rsqrtf(va + EPS);
        scq[t] = sc; shq[t] = bf2f(q_be[t]) - m * sc;
        m  = (float)(stK[t] * (double)inv_cnt);
        va = (float)(stK[64 + t] * (double)inv_cnt) - m * m;
        sc = bf2f(k_g[t]) * rsqrtf(va + EPS);
        sck[t] = sc; shk[t] = bf2f(k_be[t]) - m * sc;
    }
    w1[t >> 2][t & 3] = bf2f(we1w[t]);
    const int base = blockIdx.x * 64;
    #pragma unroll
    for (int i = 0; i < 16; ++i) {
        int e = i * 256 + t;
        int p = base + (e >> 6);
        float qv = 0.f, kv = 0.f;
        if (p < n) { qv = bf2f(qp[p * 64 + (e & 63)]); kv = bf2f(kp[p * 64 + (e & 63)]); }
        q_l[e >> 6][e & 63] = qv; k_l[e >> 6][e & 63] = kv;
    }
    __syncthreads();
    const int p = t & 63, g = t >> 6;
    float sq = 0.f, sk = 0.f;
    #pragma unroll
    for (int k = 0; k < 64; ++k) {
        float qv = fmaxf(q_l[p][k] * scq[k] + shq[k], 0.f);
        float kv = fmaxf(k_l[p][k] * sck[k] + shk[k], 0.f);
        sq += qv * w1[k][g];
        sk += kv * w1[k][g];
    }
    const int pp = base + p;
    if (pp < n) { qw1[pp * 4 + g] = sq; kw1[pp * 4 + g] = sk; }
}

// ---- pb stats: sum/sumsq of u = pos@pb1_w + pb1_b over all (n,s) per channel ----
__global__ __launch_bounds__(256) void pb_stats_kernel(
    const bf16* __restrict__ coord, const int* __restrict__ knn,
    const bf16* __restrict__ pb1w, const bf16* __restrict__ pb1b,
    double* __restrict__ st)
{
    const int t = threadIdx.x, c = t & 63, rg = t >> 6;
    const float w0 = bf2f(pb1w[c]), w1 = bf2f(pb1w[64 + c]), w2 = bf2f(pb1w[128 + c]), b = bf2f(pb1b[c]);
    float ls = 0.f, ls2 = 0.f;
    for (int base = blockIdx.x * 4; base < N_ROWS; base += gridDim.x * 4) {
        const int r = base + rg;
        const int nn = r >> 4;
        const int j = knn[r];
        const float mk = (j >= 0) ? 1.f : 0.f;
        const int js = j < 0 ? 0 : j;
        const float px = (bf2f(coord[js * 3 + 0]) - bf2f(coord[nn * 3 + 0])) * mk;
        const float py = (bf2f(coord[js * 3 + 1]) - bf2f(coord[nn * 3 + 1])) * mk;
        const float pz = (bf2f(coord[js * 3 + 2]) - bf2f(coord[nn * 3 + 2])) * mk;
        const float u = px * w0 + py * w1 + pz * w2 + b;
        ls += u; ls2 += u * u;
    }
    __shared__ float redS[4][64], redS2[4][64];
    redS[rg][c] = ls; redS2[rg][c] = ls2;
    __syncthreads();
    if (t < 64) atomicAdd(&st[t], (double)(redS[0][t] + redS[1][t] + redS[2][t] + redS[3][t]));
    else if (t < 128) {
        int cc = t - 64;
        atomicAdd(&st[64 + cc], (double)(redS2[0][cc] + redS2[1][cc] + redS2[2][cc] + redS2[3][cc]));
    }
}

// ---- wp: per-row (thread-serial) wp = mask*kw1[idx] - qw1[n] + t@W_pe + b_pe ; stats ----
__global__ __launch_bounds__(256) void wp_kernel(
    const bf16* __restrict__ coord, const int* __restrict__ knn,
    const bf16* __restrict__ pb1w, const bf16* __restrict__ pb1b,
    const double* __restrict__ stPB, const bf16* __restrict__ pb_g, const bf16* __restrict__ pb_be,
    const float* __restrict__ W_pe, const float* __restrict__ b_pe,
    const float* __restrict__ qw1, const float* __restrict__ kw1,
    float4* __restrict__ wp, double* __restrict__ stWE, float inv_cnt)
{
    __shared__ float cf[64][8];
    __shared__ float bpe_l[4];
    __shared__ float red[8][256];
    const int t = threadIdx.x;
    if (t < 64) {
        float m  = (float)(stPB[t] * (double)inv_cnt);
        float va = (float)(stPB[64 + t] * (double)inv_cnt) - m * m;
        float sc = bf2f(pb_g[t]) * rsqrtf(va + EPS);
        float sh = bf2f(pb_be[t]) - m * sc;
        cf[t][0] = bf2f(pb1w[t]) * sc;
        cf[t][1] = bf2f(pb1w[64 + t]) * sc;
        cf[t][2] = bf2f(pb1w[128 + t]) * sc;
        cf[t][3] = bf2f(pb1b[t]) * sc + sh;
        cf[t][4] = W_pe[t * 4 + 0];
        cf[t][5] = W_pe[t * 4 + 1];
        cf[t][6] = W_pe[t * 4 + 2];
        cf[t][7] = W_pe[t * 4 + 3];
    }
    if (t < 4) bpe_l[t] = b_pe[t];
    __syncthreads();
    float sg0 = 0.f, sg1 = 0.f, sg2 = 0.f, sg3 = 0.f;
    float q0 = 0.f, q1 = 0.f, q2 = 0.f, q3 = 0.f;
    const int stride = gridDim.x * 256;
    for (int r = blockIdx.x * 256 + t; r < N_ROWS; r += stride) {
        const int nn = r >> 4;
        const int j = knn[r];
        const float mk = (j >= 0) ? 1.f : 0.f;
        const int js = j < 0 ? 0 : j;
        const float px = (bf2f(coord[js * 3 + 0]) - bf2f(coord[nn * 3 + 0])) * mk;
        const float py = (bf2f(coord[js * 3 + 1]) - bf2f(coord[nn * 3 + 1])) * mk;
        const float pz = (bf2f(coord[js * 3 + 2]) - bf2f(coord[nn * 3 + 2])) * mk;
        float p0 = bpe_l[0], p1 = bpe_l[1], p2 = bpe_l[2], p3 = bpe_l[3];
        #pragma unroll
        for (int c = 0; c < 64; ++c) {
            float tt = fmaxf(px * cf[c][0] + py * cf[c][1] + pz * cf[c][2] + cf[c][3], 0.f);
            p0 += tt * cf[c][4]; p1 += tt * cf[c][5]; p2 += tt * cf[c][6]; p3 += tt * cf[c][7];
        }
        float4 val;
        val.x = mk * kw1[js * 4 + 0] - qw1[nn * 4 + 0] + p0;
        val.y = mk * kw1[js * 4 + 1] - qw1[nn * 4 + 1] + p1;
        val.z = mk * kw1[js * 4 + 2] - qw1[nn * 4 + 2] + p2;
        val.w = mk * kw1[js * 4 + 3] - qw1[nn * 4 + 3] + p3;
        wp[r] = val;
        sg0 += val.x; sg1 += val.y; sg2 += val.z; sg3 += val.w;
        q0 += val.x * val.x; q1 += val.y * val.y; q2 += val.z * val.z; q3 += val.w * val.w;
    }
    red[0][t] = sg0; red[1][t] = sg1; red[2][t] = sg2; red[3][t] = sg3;
    red[4][t] = q0;  red[5][t] = q1;  red[6][t] = q2;  red[7][t] = q3;
    __syncthreads();
    if (t < 8) {
        float s = 0.f;
        for (int i = 0; i < 256; ++i) s += red[t][i];
        atomicAdd(&stWE[t], (double)s);
    }
}

// ---- attn: softmax weights + a = sum_s w*(v[idx]+peb) via Tg factorization ; stats of a ----
__global__ __launch_bounds__(256) void attn_kernel(
    const bf16* __restrict__ coord, const int* __restrict__ knn,
    const bf16* __restrict__ pb1w, const bf16* __restrict__ pb1b,
    const double* __restrict__ stPB, const bf16* __restrict__ pb_g, const bf16* __restrict__ pb_be,
    const double* __restrict__ stWE, const bf16* __restrict__ we_g, const bf16* __restrict__ we_be,
    const bf16* __restrict__ we2w, const bf16* __restrict__ we2b,
    const bf16* __restrict__ pb2w, const bf16* __restrict__ pb2b,
    const float* __restrict__ wp, const bf16* __restrict__ v,
    bf16* __restrict__ a_out, double* __restrict__ stN2, float inv_nr)
{
    __shared__ float pb2_l[64][64];
    __shared__ float t_l[4][16][64];
    __shared__ float tg_l[4][4][64];
    __shared__ float redS[4][64], redS2[4][64];
    const int t = threadIdx.x, c = t & 63, wv = t >> 6, g = c >> 4;
    #pragma unroll
    for (int i = 0; i < 16; ++i) { int e = i * 256 + t; pb2_l[e >> 6][e & 63] = bf2f(pb2w[e]); }
    const float w0 = bf2f(pb1w[c]), w1 = bf2f(pb1w[64 + c]), w2 = bf2f(pb1w[128 + c]), bb = bf2f(pb1b[c]);
    float scPB, shPB;
    {
        float m  = (float)(stPB[c] * (double)inv_nr);
        float va = (float)(stPB[64 + c] * (double)inv_nr) - m * m;
        scPB = bf2f(pb_g[c]) * rsqrtf(va + EPS);
        shPB = bf2f(pb_be[c]) - m * scPB;
    }
    float scW[4], shW[4], w2wv[4];
    #pragma unroll
    for (int gg = 0; gg < 4; ++gg) {
        float m  = (float)(stWE[gg] * (double)inv_nr);
        float va = (float)(stWE[4 + gg] * (double)inv_nr) - m * m;
        float sc = bf2f(we_g[gg]) * rsqrtf(va + EPS);
        scW[gg] = sc; shW[gg] = bf2f(we_be[gg]) - m * sc;
        w2wv[gg] = bf2f(we2w[gg * 4 + g]);
    }
    const float w2bg = bf2f(we2b[g]);
    const float pb2bc = bf2f(pb2b[c]);
    float sa = 0.f, sa2 = 0.f;
    __syncthreads();
    for (int pbase = blockIdx.x * 4; pbase < N_PTS; pbase += gridDim.x * 4) {
        const int p = pbase + wv;
        const bool act = p < N_PTS;
        float wgt[16];
        if (act) {
            float mx = -1e30f;
            const float4* wp4 = (const float4*)wp;
            #pragma unroll
            for (int s = 0; s < 16; ++s) {
                float4 q4 = wp4[p * 16 + s];
                float r0 = fmaxf(q4.x * scW[0] + shW[0], 0.f);
                float r1 = fmaxf(q4.y * scW[1] + shW[1], 0.f);
                float r2 = fmaxf(q4.z * scW[2] + shW[2], 0.f);
                float r3 = fmaxf(q4.w * scW[3] + shW[3], 0.f);
                float val = r0 * w2wv[0] + r1 * w2wv[1] + r2 * w2wv[2] + r3 * w2wv[3] + w2bg;
                wgt[s] = val; mx = fmaxf(mx, val);
            }
            float ssum = 0.f;
            #pragma unroll
            for (int s = 0; s < 16; ++s) { float e = __expf(wgt[s] - mx); wgt[s] = e; ssum += e; }
            const float inv = 1.f / ssum;
            const float cx = bf2f(coord[p * 3 + 0]), cy = bf2f(coord[p * 3 + 1]), cz = bf2f(coord[p * 3 + 2]);
            #pragma unroll
            for (int s = 0; s < 16; ++s) {
                const int j = knn[p * 16 + s];
                const float mk = (j >= 0) ? 1.f : 0.f;
                const int js = j < 0 ? 0 : j;
                wgt[s] *= inv * mk;
                const float px = (bf2f(coord[js * 3 + 0]) - cx) * mk;
                const float py = (bf2f(coord[js * 3 + 1]) - cy) * mk;
                const float pz = (bf2f(coord[js * 3 + 2]) - cz) * mk;
                const float u = px * w0 + py * w1 + pz * w2 + bb;
                t_l[wv][s][c] = fmaxf(u * scPB + shPB, 0.f);
            }
        }
        __syncthreads();
        if (act) {
            const int kb = c & 15;
            #pragma unroll
            for (int m2 = 0; m2 < 4; ++m2) {
                const int k = kb + 16 * m2;
                float s2 = 0.f;
                #pragma unroll
                for (int s = 0; s < 16; ++s) s2 += wgt[s] * t_l[wv][s][k];
                tg_l[wv][g][k] = s2;
            }
        }
        __syncthreads();
        if (act) {
            float Wg = 0.f;
            #pragma unroll
            for (int s = 0; s < 16; ++s) Wg += wgt[s];
            float vs = 0.f;
            #pragma unroll
            for (int s = 0; s < 16; ++s) {
                const int j = knn[p * 16 + s];
                const int js = j < 0 ? 0 : j;
                vs += wgt[s] * bf2f(v[js * 64 + c]);
            }
            float acc = vs + pb2bc * Wg;
            #pragma unroll
            for (int k = 0; k < 64; ++k) acc += tg_l[wv][g][k] * pb2_l[k][c];
            a_out[p * 64 + c] = f2bf(acc);
            sa += acc; sa2 += acc * acc;
        }
    }
    redS[wv][c] = sa; redS2[wv][c] = sa2;
    __syncthreads();
    if (t < 64) atomicAdd(&stN2[t], (double)(redS[0][t] + redS[1][t] + redS[2][t] + redS[3][t]));
    else if (t < 128) {
        int cc = t - 64;
        atomicAdd(&stN2[64 + cc], (double)(redS2[0][cc] + redS2[1][cc] + redS2[2][cc] + redS2[3][cc]));
    }
}

// ---- residual: out = relu(identity + bn3(t3)); final write dual-dtype per flag ----
__global__ __launch_bounds__(256) void residual_kernel(
    const bf16* __restrict__ t3, const double* __restrict__ stN3,
    const bf16* __restrict__ n3_g, const bf16* __restrict__ n3_b,
    const bf16* __restrict__ id, bf16* __restrict__ outB, float* __restrict__ outF,
    const int* __restrict__ flag, int total, float inv_n)
{
    int i = blockIdx.x * 256 + threadIdx.x;
    if (i >= total) return;
    const int c = i & 63;
    float m  = (float)(stN3[c] * (double)inv_n);
    float va = (float)(stN3[64 + c] * (double)inv_n) - m * m;
    float sc = bf2f(n3_g[c]) * rsqrtf(va + EPS);
    float sh = bf2f(n3_b[c]) - m * sc;
    float val = fmaxf(bf2f(id[i]) + bf2f(t3[i]) * sc + sh, 0.f);
    if (flag && *flag) outF[i] = val;
    else outB[i] = f2bf(val);
}

extern "C" void kernel_launch(void* const* d_in, const int* in_sizes, int n_in,
                              void* d_out, int out_size, void* d_ws, size_t ws_size,
                              hipStream_t stream)
{
    const int* knn = (const int*)d_in[32];

    // ---- workspace layout ----
    double* stats = (double*)d_ws;        // 776 doubles (bytes 0..6207)
    double* st1  = stats;
    double* stQ  = stats + 128;
    double* stK  = stats + 256;
    double* stPB = stats + 384;
    double* stWE = stats + 512;           // 8
    double* stN2 = stats + 520;
    double* stN3 = stats + 648;           // end 776
    int* flag = (int*)((char*)d_ws + 7168);

    float* fb   = (float*)((char*)d_ws + 8192);
    float* W_pe = fb;                     // 256
    float* b_pe = fb + 256;               // 4 (pad to 288)
    float* qw1  = fb + 288;               // N*4
    float* kw1  = qw1 + N_PTS * 4;        // N*4
    float* t1f  = kw1 + N_PTS * 4;        // N*64 f32 (reused as wp: (N*S) float4)
    bf16* qb  = (bf16*)(t1f + N_PTS * 64);  // N*64 bf16 (q pre-act -> a)
    bf16* kb  = qb + N_PTS * 64;            // N*64 bf16 (k pre-act -> t3)
    bf16* vb  = kb + N_PTS * 64;            // N*64 bf16 (v)
    bf16* xbb = vb + N_PTS * 64;            // N*64 bf16 (x between depths)
    bf16* canon = xbb + N_PTS * 64;         // canonical bf16 copies of float inputs

    // canonical offsets from in_sizes (inputs 0..31 are the float arrays)
    PtrTable pt; IntTable sz, off;
    int acc = 0;
    bf16* ci[32];
    for (int i = 0; i < 32; ++i) {
        pt.p[i] = d_in[i];
        sz.v[i] = in_sizes[i];
        off.v[i] = acc;
        ci[i] = canon + acc;
        acc += in_sizes[i];
    }
    const bf16* feat  = ci[0];
    const bf16* coord = ci[1];
    const bf16* fc1_w = ci[2];
    const bf16* q_w  = ci[3];  const bf16* q_b  = ci[4];  const bf16* q_g  = ci[5];  const bf16* q_be = ci[6];
    const bf16* k_w  = ci[7];  const bf16* k_b  = ci[8];  const bf16* k_g  = ci[9];  const bf16* k_be = ci[10];
    const bf16* v_w  = ci[11]; const bf16* v_b  = ci[12];
    const bf16* pb1_w = ci[13]; const bf16* pb1_b = ci[14]; const bf16* pb_g = ci[15]; const bf16* pb_be = ci[16];
    const bf16* pb2_w = ci[17]; const bf16* pb2_b = ci[18];
    const bf16* we1_w = ci[19]; const bf16* we1_b = ci[20]; const bf16* we_g = ci[21]; const bf16* we_be = ci[22];
    const bf16* we2_w = ci[23]; const bf16* we2_b = ci[24];
    const bf16* fc3_w = ci[25];
    const bf16* n1_g = ci[26]; const bf16* n1_b = ci[27];
    const bf16* n2_g = ci[28]; const bf16* n2_b = ci[29];
    const bf16* n3_g = ci[30]; const bf16* n3_b = ci[31];

    const int GG = (N_PTS + 63) / 64;     // 782
    const float invN = 1.f / (float)N_PTS;
    const float invR = 1.f / (float)N_ROWS;

    sniff_kernel<<<1, 256, 0, stream>>>(d_in[0], flag);
    canon_kernel<<<512, 256, 0, stream>>>(flag, pt, sz, off, canon);

    for (int d = 0; d < 2; ++d) {
        hipMemsetAsync(stats, 0, 776 * sizeof(double), stream);
        prep_kernel<<<1, 256, 0, stream>>>(pb2_w + d * 4096, pb2_b + d * 64,
                                           we1_w + d * 256, we1_b + d * 4, W_pe, b_pe);
        // A1: t1 = x @ fc1_w ; stats1
        gemm64_kernel<<<GG, 256, 0, stream>>>(nullptr, d == 0 ? feat : xbb,
                                              nullptr, nullptr, nullptr, 0.f,
                                              fc1_w + d * 4096, nullptr, t1f, nullptr, st1, N_PTS);
        // A2: q/k/v from h = relu(bn1(t1))
        gemm64_kernel<<<GG, 256, 0, stream>>>(t1f, nullptr, st1, n1_g + d * 64, n1_b + d * 64, invN,
                                              q_w + d * 4096, q_b + d * 64, nullptr, qb, stQ, N_PTS);
        gemm64_kernel<<<GG, 256, 0, stream>>>(t1f, nullptr, st1, n1_g + d * 64, n1_b + d * 64, invN,
                                              k_w + d * 4096, k_b + d * 64, nullptr, kb, stK, N_PTS);
        gemm64_kernel<<<GG, 256, 0, stream>>>(t1f, nullptr, st1, n1_g + d * 64, n1_b + d * 64, invN,
                                              v_w + d * 4096, v_b + d * 64, nullptr, vb, nullptr, N_PTS);
        // A3: qw1/kw1
        qkw1_kernel<<<GG, 256, 0, stream>>>(qb, kb, stQ, stK, q_g + d * 64, q_be + d * 64,
                                            k_g + d * 64, k_be + d * 64,
                                            we1_w + d * 256, qw1, kw1, N_PTS, invN);
        // B1: pb bn stats
        pb_stats_kernel<<<1024, 256, 0, stream>>>(coord, knn, pb1_w + d * 192, pb1_b + d * 64, stPB);
        // B2: wp (into t1f) + we stats
        wp_kernel<<<1024, 256, 0, stream>>>(coord, knn, pb1_w + d * 192, pb1_b + d * 64,
                                            stPB, pb_g + d * 64, pb_be + d * 64,
                                            W_pe, b_pe, qw1, kw1, (float4*)t1f, stWE, invR);
        // B3: attention -> a (into qb) + n2 stats
        attn_kernel<<<1024, 256, 0, stream>>>(coord, knn, pb1_w + d * 192, pb1_b + d * 64,
                                              stPB, pb_g + d * 64, pb_be + d * 64,
                                              stWE, we_g + d * 4, we_be + d * 4,
                                              we2_w + d * 16, we2_b + d * 4,
                                              pb2_w + d * 4096, pb2_b + d * 64,
                                              t1f, vb, qb, stN2, invR);
        // C1: t3 = relu(bn2(a)) @ fc3_w ; n3 stats (t3 into kb)
        gemm64_kernel<<<GG, 256, 0, stream>>>(nullptr, qb, stN2, n2_g + d * 64, n2_b + d * 64, invN,
                                              fc3_w + d * 4096, nullptr, nullptr, kb, stN3, N_PTS);
        // C2: x' = relu(identity + bn3(t3))
        residual_kernel<<<(N_PTS * 64 + 255) / 256, 256, 0, stream>>>(
            kb, stN3, n3_g + d * 64, n3_b + d * 64,
            d == 0 ? feat : xbb,
            d == 0 ? xbb : (bf16*)d_out,
            d == 0 ? nullptr : (float*)d_out,
            d == 0 ? nullptr : flag,
            N_PTS * 64, invN);
    }
}